// Round 1
// baseline (1139.147 us; speedup 1.0000x reference)
//
#include <hip/hip_runtime.h>

#define N_ROWS 65536
#define D 256
#define K 1024
#define DECAYF 0.99f
#define OMDF 0.01f
#define EPSF 1e-5f

// ---------------- codebook norms ----------------
__global__ __launch_bounds__(256) void norms_kernel(const float* __restrict__ cb,
                                                    float* __restrict__ cnorm) {
    const int row = blockIdx.x * 4 + (threadIdx.x >> 6);
    const int lane = threadIdx.x & 63;
    const float4 v = *reinterpret_cast<const float4*>(cb + row * D + lane * 4);
    float s = v.x * v.x + v.y * v.y + v.z * v.z + v.w * v.w;
    #pragma unroll
    for (int m = 32; m; m >>= 1) s += __shfl_xor(s, m);
    if (lane == 0) cnorm[row] = s;
}

// ---------------- argmin over codebook ----------------
#define TN 64
#define TK 256
#define DC 32
#define CSTR 34  // LDS row stride for codebook tile (bank-conflict-free for kg-strided reads)

__global__ __launch_bounds__(256) void argmin_kernel(const float* __restrict__ x,
                                                     const float* __restrict__ cb,
                                                     const float* __restrict__ cnorm,
                                                     int* __restrict__ idx_out,
                                                     float* __restrict__ counts) {
    __shared__ float Cs[TK * CSTR];  // 34816 B
    __shared__ float Xs[TN * DC];    // 8192 B
    const int tid = threadIdx.x;
    const int wave = tid >> 6;
    const int lane = tid & 63;
    const int rg = lane >> 5;   // 0/1: row-group within wave
    const int kg = lane & 31;   // k-group lane
    const int n0 = blockIdx.x * TN;
    const int rbase = wave * 16 + rg * 8;  // this thread's 8 rows start here

    float bestv[8];
    int besti[8];
    #pragma unroll
    for (int i = 0; i < 8; ++i) { bestv[i] = 3.4e38f; besti[i] = 0; }

    for (int kt = 0; kt < K / TK; ++kt) {
        float acc[8][8];
        #pragma unroll
        for (int i = 0; i < 8; ++i)
            #pragma unroll
            for (int j = 0; j < 8; ++j) acc[i][j] = 0.f;

        for (int dc = 0; dc < D / DC; ++dc) {
            const int d0 = dc * DC;
            __syncthreads();
            // stage codebook tile: 256 rows x 32 floats
            {
                const int r = tid >> 3;          // 0..31
                const int c = (tid & 7) * 4;     // 0,4,..,28
                #pragma unroll
                for (int p = 0; p < 8; ++p) {
                    const int row = p * 32 + r;
                    const float4 v = *reinterpret_cast<const float4*>(
                        cb + (size_t)(kt * TK + row) * D + d0 + c);
                    float* dst = &Cs[row * CSTR + c];
                    *reinterpret_cast<float2*>(dst) = make_float2(v.x, v.y);
                    *reinterpret_cast<float2*>(dst + 2) = make_float2(v.z, v.w);
                }
            }
            // stage X tile: 64 rows x 32 floats
            {
                const int r = tid >> 2;          // 0..63
                const int c = (tid & 3) * 8;     // 0,8,16,24
                const float4 a = *reinterpret_cast<const float4*>(x + (size_t)(n0 + r) * D + d0 + c);
                const float4 b = *reinterpret_cast<const float4*>(x + (size_t)(n0 + r) * D + d0 + c + 4);
                *reinterpret_cast<float4*>(&Xs[r * DC + c]) = a;
                *reinterpret_cast<float4*>(&Xs[r * DC + c + 4]) = b;
            }
            __syncthreads();
            // register-tiled dot products: 8 rows x 8 codes per thread
            #pragma unroll 4
            for (int d2 = 0; d2 < DC; d2 += 2) {
                float2 xv[8], cv[8];
                #pragma unroll
                for (int i = 0; i < 8; ++i)
                    xv[i] = *reinterpret_cast<const float2*>(&Xs[(rbase + i) * DC + d2]);
                #pragma unroll
                for (int j = 0; j < 8; ++j)
                    cv[j] = *reinterpret_cast<const float2*>(&Cs[(j * 32 + kg) * CSTR + d2]);
                #pragma unroll
                for (int i = 0; i < 8; ++i)
                    #pragma unroll
                    for (int j = 0; j < 8; ++j)
                        acc[i][j] += xv[i].x * cv[j].x + xv[i].y * cv[j].y;
            }
        }
        // fold this k-tile into running argmin (ascending k => first-min tie-break)
        #pragma unroll
        for (int j = 0; j < 8; ++j) {
            const int k = kt * TK + j * 32 + kg;
            const float cn = cnorm[k];
            #pragma unroll
            for (int i = 0; i < 8; ++i) {
                const float dist = cn - 2.f * acc[i][j];
                if (dist < bestv[i]) { bestv[i] = dist; besti[i] = k; }
            }
        }
    }
    // cross-lane argmin over the 32 kg lanes (both halves reduce independently)
    #pragma unroll
    for (int i = 0; i < 8; ++i) {
        float v = bestv[i];
        int b = besti[i];
        #pragma unroll
        for (int m = 16; m; m >>= 1) {
            const float ov = __shfl_xor(v, m);
            const int ob = __shfl_xor(b, m);
            if (ov < v || (ov == v && ob < b)) { v = ov; b = ob; }
        }
        bestv[i] = v; besti[i] = b;
    }
    if (kg == 0) {
        #pragma unroll
        for (int i = 0; i < 8; ++i) {
            idx_out[n0 + rbase + i] = besti[i];
            atomicAdd(&counts[besti[i]], 1.0f);
        }
    }
}

// ---------------- quantized gather + dw scatter ----------------
__global__ __launch_bounds__(256) void quant_dw_kernel(const float* __restrict__ x,
                                                       const float* __restrict__ cb,
                                                       const int* __restrict__ idx,
                                                       float* __restrict__ quant,
                                                       float* __restrict__ dw) {
    const int n = blockIdx.x * 4 + (threadIdx.x >> 6);
    const int lane = threadIdx.x & 63;
    const int i = idx[n];
    const float4 c = *reinterpret_cast<const float4*>(cb + (size_t)i * D + lane * 4);
    *reinterpret_cast<float4*>(quant + (size_t)n * D + lane * 4) = c;
    const float4 xv = *reinterpret_cast<const float4*>(x + (size_t)n * D + lane * 4);
    float* dst = dw + (size_t)i * D + lane * 4;
    atomicAdd(dst + 0, xv.x);
    atomicAdd(dst + 1, xv.y);
    atomicAdd(dst + 2, xv.z);
    atomicAdd(dst + 3, xv.w);
}

// ---------------- one-hot encodings ----------------
__global__ __launch_bounds__(256) void enc_kernel(const int* __restrict__ idx,
                                                  float* __restrict__ enc) {
    const int total = N_ROWS * (K / 4);  // float4 groups
    for (int g = blockIdx.x * blockDim.x + threadIdx.x; g < total;
         g += gridDim.x * blockDim.x) {
        const int n = g >> 8;
        const int k0 = (g & 255) * 4;
        const int i = idx[n];
        float4 v;
        v.x = (k0 == i) ? 1.f : 0.f;
        v.y = (k0 + 1 == i) ? 1.f : 0.f;
        v.z = (k0 + 2 == i) ? 1.f : 0.f;
        v.w = (k0 + 3 == i) ? 1.f : 0.f;
        *reinterpret_cast<float4*>(enc + (size_t)g * 4) = v;
    }
}

// ---------------- cluster-size EMA + Laplace ----------------
__global__ __launch_bounds__(1024) void cs_kernel(const float* __restrict__ ema_cs,
                                                  const float* __restrict__ counts,
                                                  float* __restrict__ cs_out) {
    __shared__ float red[16];
    __shared__ float n_sh;
    const int k = threadIdx.x;
    const float c = ema_cs[k] * DECAYF + OMDF * counts[k];
    float s = c;
    #pragma unroll
    for (int m = 32; m; m >>= 1) s += __shfl_xor(s, m);
    if ((k & 63) == 0) red[k >> 6] = s;
    __syncthreads();
    if (k == 0) {
        float n = 0.f;
        for (int w = 0; w < 16; ++w) n += red[w];
        n_sh = n;
    }
    __syncthreads();
    const float n = n_sh;
    cs_out[k] = (c + EPSF) / (n + c * EPSF) * n;
}

// ---------------- ema_w + new codebook ----------------
__global__ __launch_bounds__(256) void ema_kernel(const float* __restrict__ ema_w,
                                                  const float* __restrict__ dw,
                                                  const float* __restrict__ cs,
                                                  float* __restrict__ w_out,
                                                  float* __restrict__ cb_out) {
    const int e4 = blockIdx.x * blockDim.x + threadIdx.x;  // 65536 float4 groups
    const int k = e4 >> 6;
    const float csk = cs[k];
    const float4 w = *reinterpret_cast<const float4*>(ema_w + (size_t)e4 * 4);
    const float4 d = *reinterpret_cast<const float4*>(dw + (size_t)e4 * 4);
    float4 nw, nc;
    nw.x = w.x * DECAYF + OMDF * d.x;
    nw.y = w.y * DECAYF + OMDF * d.y;
    nw.z = w.z * DECAYF + OMDF * d.z;
    nw.w = w.w * DECAYF + OMDF * d.w;
    nc.x = nw.x / csk; nc.y = nw.y / csk; nc.z = nw.z / csk; nc.w = nw.w / csk;
    *reinterpret_cast<float4*>(w_out + (size_t)e4 * 4) = nw;
    *reinterpret_cast<float4*>(cb_out + (size_t)e4 * 4) = nc;
}

extern "C" void kernel_launch(void* const* d_in, const int* in_sizes, int n_in,
                              void* d_out, int out_size, void* d_ws, size_t ws_size,
                              hipStream_t stream) {
    (void)in_sizes; (void)n_in; (void)out_size; (void)ws_size;
    const float* x      = (const float*)d_in[0];  // [65536,256]
    const float* cb     = (const float*)d_in[1];  // [1024,256]
    const float* ema_w  = (const float*)d_in[2];  // [1024,256]
    const float* ema_cs = (const float*)d_in[3];  // [1024]

    float* out    = (float*)d_out;
    float* quant  = out;                   // 16777216
    float* enc    = quant + 16777216;      // 67108864
    float* cs_out = enc + 67108864;        // 1024
    float* w_out  = cs_out + 1024;         // 262144
    float* cb_out = w_out + 262144;        // 262144

    float* ws     = (float*)d_ws;
    float* counts = ws;                    // 1024
    float* cnorm  = ws + 1024;             // 1024
    float* dw     = ws + 2048;             // 262144
    int*   idx    = (int*)(ws + 2048 + 262144);  // 65536 ints

    hipMemsetAsync(ws, 0, (size_t)(2048 + 262144) * sizeof(float), stream);
    norms_kernel<<<K / 4, 256, 0, stream>>>(cb, cnorm);
    argmin_kernel<<<N_ROWS / TN, 256, 0, stream>>>(x, cb, cnorm, idx, counts);
    quant_dw_kernel<<<N_ROWS / 4, 256, 0, stream>>>(x, cb, idx, quant, dw);
    enc_kernel<<<2048, 256, 0, stream>>>(idx, enc);
    cs_kernel<<<1, 1024, 0, stream>>>(ema_cs, counts, cs_out);
    ema_kernel<<<65536 / 256, 256, 0, stream>>>(ema_w, dw, cs_out, w_out, cb_out);
}

// Round 2
// 725.932 us; speedup vs baseline: 1.5692x; 1.5692x over previous
//
#include <hip/hip_runtime.h>

#define N_ROWS 65536
#define D 256
#define K 1024
#define DECAYF 0.99f
#define OMDF 0.01f
#define EPSF 1e-5f

typedef _Float16 f16;
typedef _Float16 f16x8 __attribute__((ext_vector_type(8)));
typedef float f32x16 __attribute__((ext_vector_type(16)));

// ---------------- codebook norms (fp32, exact as before) ----------------
__global__ __launch_bounds__(256) void norms_kernel(const float* __restrict__ cb,
                                                    float* __restrict__ cnorm) {
    const int row = blockIdx.x * 4 + (threadIdx.x >> 6);
    const int lane = threadIdx.x & 63;
    const float4 v = *reinterpret_cast<const float4*>(cb + row * D + lane * 4);
    float s = v.x * v.x + v.y * v.y + v.z * v.z + v.w * v.w;
    #pragma unroll
    for (int m = 32; m; m >>= 1) s += __shfl_xor(s, m);
    if (lane == 0) cnorm[row] = s;
}

// ---------------- codebook split hi/lo fp16, pre-swizzled tile layout ----------------
// ws_B granule g (16B): g = ((ct*4+dk)*256 + c)*16 + slot_phys
// slot_phys = slot_logical ^ (c & 7); slot_logical = v*8 + ks*2 + h
// content: fp16 of cb[ct*256+c][dk*64 + ks*16 + h*8 + e], e=0..7; v=0 hi, v=1 lo
__global__ __launch_bounds__(256) void split_cb_kernel(const float* __restrict__ cb,
                                                       char* __restrict__ wsB) {
    const int g = blockIdx.x * 256 + threadIdx.x;   // 0..65535
    const int sp = g & 15;
    const int c = (g >> 4) & 255;
    const int sd = g >> 12;                          // ct*4+dk
    const int ct = sd >> 2, dk = sd & 3;
    const int sl = sp ^ (c & 7);
    const int v = sl >> 3, ks = (sl >> 1) & 3, h = sl & 1;
    const float* src = cb + (size_t)(ct * 256 + c) * D + dk * 64 + ks * 16 + h * 8;
    f16 out[8];
    #pragma unroll
    for (int e = 0; e < 8; ++e) {
        const float f = src[e];
        const f16 hi = (f16)f;
        out[e] = v ? (f16)(f - (float)hi) : hi;
    }
    *reinterpret_cast<f16x8*>(wsB + (size_t)g * 16) = *reinterpret_cast<f16x8*>(out);
}

// ---------------- MFMA argmin ----------------
// block: 256 thr = 4 waves (2 row-waves x 2 col-waves); block tile 64 rows x 256 codes per ct
// wave tile: 32 rows x 128 codes (1 row-frag x 4 col-frags of 32x32x16_f16)
// LDS: A[64 rows][16 slots x 16B] = 16KB  |  B[256 codes][16 slots x 16B] = 64KB  -> 80KB
__global__ __launch_bounds__(256, 2) void argmin_mfma_kernel(
        const float* __restrict__ x, const char* __restrict__ wsB,
        const float* __restrict__ cnorm, int* __restrict__ idx_out,
        float* __restrict__ counts) {
    __shared__ char smem[81920];
    char* Alds = smem;
    char* Blds = smem + 16384;
    const int tid = threadIdx.x;
    const int wave = tid >> 6;
    const int lane = tid & 63;
    const int rw = wave >> 1;       // row-wave 0/1
    const int cw = wave & 1;        // col-wave 0/1
    const int l31 = lane & 31;
    const int h = lane >> 5;
    const int n0 = blockIdx.x * 64;

    float bestv[16];
    int besti[16];
    #pragma unroll
    for (int r = 0; r < 16; ++r) { bestv[r] = 3.4e38f; besti[r] = 0; }

    // staging decode (A): row/chunk this thread stages
    const int s_row = tid >> 2;     // 0..63
    const int s_c4 = tid & 3;       // kstep chunk (16 f32)

    for (int ct = 0; ct < 4; ++ct) {
        f32x16 acc[4];
        #pragma unroll
        for (int cf = 0; cf < 4; ++cf)
            #pragma unroll
            for (int r = 0; r < 16; ++r) acc[cf][r] = 0.f;

        for (int dks = 0; dks < 4; ++dks) {
            const int dk = (ct & 1) ? (3 - dks) : dks;  // serpentine: A reusable at ct boundary
            __syncthreads();
            if (!(ct > 0 && dks == 0)) {
                // stage A: 64 rows x 64 dims fp32 -> hi/lo fp16, swizzled
                const float4* xs = reinterpret_cast<const float4*>(
                    x + (size_t)(n0 + s_row) * D + dk * 64 + s_c4 * 16);
                float f[16];
                {
                    const float4 f0 = xs[0], f1 = xs[1], f2 = xs[2], f3 = xs[3];
                    f[0]=f0.x; f[1]=f0.y; f[2]=f0.z; f[3]=f0.w;
                    f[4]=f1.x; f[5]=f1.y; f[6]=f1.z; f[7]=f1.w;
                    f[8]=f2.x; f[9]=f2.y; f[10]=f2.z; f[11]=f2.w;
                    f[12]=f3.x; f[13]=f3.y; f[14]=f3.z; f[15]=f3.w;
                }
                f16 hi[16], lo[16];
                #pragma unroll
                for (int e = 0; e < 16; ++e) {
                    hi[e] = (f16)f[e];
                    lo[e] = (f16)(f[e] - (float)hi[e]);
                }
                const int sw = s_row & 7;
                char* Abase = Alds + s_row * 256;
                *reinterpret_cast<f16x8*>(Abase + (((s_c4 * 2 + 0) ^ sw) * 16)) = *reinterpret_cast<f16x8*>(&hi[0]);
                *reinterpret_cast<f16x8*>(Abase + (((s_c4 * 2 + 1) ^ sw) * 16)) = *reinterpret_cast<f16x8*>(&hi[8]);
                *reinterpret_cast<f16x8*>(Abase + (((8 + s_c4 * 2 + 0) ^ sw) * 16)) = *reinterpret_cast<f16x8*>(&lo[0]);
                *reinterpret_cast<f16x8*>(Abase + (((8 + s_c4 * 2 + 1) ^ sw) * 16)) = *reinterpret_cast<f16x8*>(&lo[8]);
            }
            // stage B: 64KB linear copy from pre-swizzled ws tile
            {
                const int4* gsrc = reinterpret_cast<const int4*>(wsB + ((size_t)(ct * 4 + dk) << 16));
                int4* ldst = reinterpret_cast<int4*>(Blds);
                #pragma unroll
                for (int i = 0; i < 16; ++i) ldst[tid + i * 256] = gsrc[tid + i * 256];
            }
            __syncthreads();
            // compute: 4 ksteps x (3 combos x 4 col-frags)
            const int arow = rw * 32 + l31;
            const int asw = arow & 7;
            #pragma unroll
            for (int ks = 0; ks < 4; ++ks) {
                const int sA = ks * 2 + h;
                const f16x8 Ah = *reinterpret_cast<const f16x8*>(Alds + arow * 256 + ((sA ^ asw) * 16));
                const f16x8 Al = *reinterpret_cast<const f16x8*>(Alds + arow * 256 + (((8 + sA) ^ asw) * 16));
                #pragma unroll
                for (int cf = 0; cf < 4; ++cf) {
                    const int bcode = cw * 128 + cf * 32 + l31;
                    const char* Bbase = Blds + bcode * 256;
                    const int bsw = bcode & 7;
                    const f16x8 Bh = *reinterpret_cast<const f16x8*>(Bbase + ((sA ^ bsw) * 16));
                    const f16x8 Bl = *reinterpret_cast<const f16x8*>(Bbase + (((8 + sA) ^ bsw) * 16));
                    acc[cf] = __builtin_amdgcn_mfma_f32_32x32x16_f16(Ah, Bh, acc[cf], 0, 0, 0);
                    acc[cf] = __builtin_amdgcn_mfma_f32_32x32x16_f16(Ah, Bl, acc[cf], 0, 0, 0);
                    acc[cf] = __builtin_amdgcn_mfma_f32_32x32x16_f16(Al, Bh, acc[cf], 0, 0, 0);
                }
            }
        }
        // fold argmin for this ct (codes ascend across cf and ct -> strict < = first-min)
        #pragma unroll
        for (int cf = 0; cf < 4; ++cf) {
            const int code = ct * 256 + cw * 128 + cf * 32 + l31;
            const float cn = cnorm[code];
            #pragma unroll
            for (int r = 0; r < 16; ++r) {
                const float dist = cn - 2.f * acc[cf][r];
                if (dist < bestv[r]) { bestv[r] = dist; besti[r] = code; }
            }
        }
    }
    // cross-lane argmin within each 32-lane group (cols), idx tie-break
    #pragma unroll
    for (int r = 0; r < 16; ++r) {
        float v = bestv[r];
        int b = besti[r];
        #pragma unroll
        for (int m = 16; m; m >>= 1) {
            const float ov = __shfl_xor(v, m);
            const int ob = __shfl_xor(b, m);
            if (ov < v || (ov == v && ob < b)) { v = ov; b = ob; }
        }
        bestv[r] = v; besti[r] = b;
    }
    __syncthreads();  // done with A region; overlay reduce buffer
    float* Sv = reinterpret_cast<float*>(smem);        // [2 cw][64 rows]
    int*   Si = reinterpret_cast<int*>(smem + 512);
    if (l31 == 0) {
        #pragma unroll
        for (int r = 0; r < 16; ++r) {
            const int row = rw * 32 + (r & 3) + 8 * (r >> 2) + 4 * h;
            Sv[cw * 64 + row] = bestv[r];
            Si[cw * 64 + row] = besti[r];
        }
    }
    __syncthreads();
    if (tid < 64) {
        const float v0 = Sv[tid], v1 = Sv[64 + tid];
        const int b0 = Si[tid], b1 = Si[64 + tid];
        const bool take1 = (v1 < v0) || (v1 == v0 && b1 < b0);
        const int b = take1 ? b1 : b0;
        idx_out[n0 + tid] = b;
        atomicAdd(&counts[b], 1.0f);
    }
}

// ---------------- quantized gather (no atomics) ----------------
__global__ __launch_bounds__(256) void quant_kernel(const float* __restrict__ cb,
                                                    const int* __restrict__ idx,
                                                    float* __restrict__ quant) {
    const int n = blockIdx.x * 4 + (threadIdx.x >> 6);
    const int lane = threadIdx.x & 63;
    const int i = idx[n];
    const float4 c = *reinterpret_cast<const float4*>(cb + (size_t)i * D + lane * 4);
    *reinterpret_cast<float4*>(quant + (size_t)n * D + lane * 4) = c;
}

// ---------------- one-hot encodings ----------------
__global__ __launch_bounds__(256) void enc_kernel(const int* __restrict__ idx,
                                                  float* __restrict__ enc) {
    const int total = N_ROWS * (K / 4);
    for (int g = blockIdx.x * blockDim.x + threadIdx.x; g < total;
         g += gridDim.x * blockDim.x) {
        const int n = g >> 8;
        const int k0 = (g & 255) * 4;
        const int i = idx[n];
        float4 v;
        v.x = (k0 == i) ? 1.f : 0.f;
        v.y = (k0 + 1 == i) ? 1.f : 0.f;
        v.z = (k0 + 2 == i) ? 1.f : 0.f;
        v.w = (k0 + 3 == i) ? 1.f : 0.f;
        *reinterpret_cast<float4*>(enc + (size_t)g * 4) = v;
    }
}

// ---------------- cs EMA + Laplace + exclusive scan of counts ----------------
__global__ __launch_bounds__(1024) void cs_scan_kernel(const float* __restrict__ ema_cs,
                                                       const float* __restrict__ counts,
                                                       float* __restrict__ cs_out,
                                                       int* __restrict__ offsets,
                                                       int* __restrict__ cursor) {
    __shared__ float red[16];
    __shared__ float n_sh;
    __shared__ int sc[1024];
    const int k = threadIdx.x;
    const float cnt = counts[k];
    const float c = ema_cs[k] * DECAYF + OMDF * cnt;
    float s = c;
    #pragma unroll
    for (int m = 32; m; m >>= 1) s += __shfl_xor(s, m);
    if ((k & 63) == 0) red[k >> 6] = s;
    const int ic = (int)cnt;
    sc[k] = ic;
    __syncthreads();
    if (k == 0) {
        float n = 0.f;
        for (int w = 0; w < 16; ++w) n += red[w];
        n_sh = n;
    }
    // Hillis-Steele inclusive scan
    for (int d = 1; d < 1024; d <<= 1) {
        const int t = (k >= d) ? sc[k - d] : 0;
        __syncthreads();
        sc[k] += t;
        __syncthreads();
    }
    const float n = n_sh;
    cs_out[k] = (c + EPSF) / (n + c * EPSF) * n;
    const int excl = sc[k] - ic;
    offsets[k] = excl;
    cursor[k] = excl;
}

// ---------------- scatter rows by code ----------------
__global__ __launch_bounds__(256) void scatter_kernel(const int* __restrict__ idx,
                                                      int* __restrict__ cursor,
                                                      int* __restrict__ rowlist) {
    const int n = blockIdx.x * 256 + threadIdx.x;
    const int i = idx[n];
    const int pos = atomicAdd(&cursor[i], 1);
    rowlist[pos] = n;
}

// ---------------- per-code sum + fused EMA-w + codebook update ----------------
__global__ __launch_bounds__(256) void code_update_kernel(const float* __restrict__ x,
                                                          const int* __restrict__ offsets,
                                                          const int* __restrict__ ends,
                                                          const int* __restrict__ rowlist,
                                                          const float* __restrict__ ema_w,
                                                          const float* __restrict__ cs,
                                                          float* __restrict__ w_out,
                                                          float* __restrict__ cb_out) {
    __shared__ float4 red[256];
    const int k = blockIdx.x;
    const int tid = threadIdx.x;
    const int rg = tid >> 6;
    const int lane = tid & 63;
    const int start = offsets[k];
    const int end = ends[k];
    float4 s = make_float4(0.f, 0.f, 0.f, 0.f);
    for (int p = start + rg; p < end; p += 4) {
        const int row = rowlist[p];
        const float4 v = *reinterpret_cast<const float4*>(x + (size_t)row * D + lane * 4);
        s.x += v.x; s.y += v.y; s.z += v.z; s.w += v.w;
    }
    red[tid] = s;
    __syncthreads();
    if (rg == 0) {
        float4 a = red[lane], b = red[64 + lane], c = red[128 + lane], d = red[192 + lane];
        s.x = a.x + b.x + c.x + d.x;
        s.y = a.y + b.y + c.y + d.y;
        s.z = a.z + b.z + c.z + d.z;
        s.w = a.w + b.w + c.w + d.w;
        const float csk = cs[k];
        const float4 w = *reinterpret_cast<const float4*>(ema_w + (size_t)k * D + lane * 4);
        float4 nw, nc;
        nw.x = w.x * DECAYF + OMDF * s.x;
        nw.y = w.y * DECAYF + OMDF * s.y;
        nw.z = w.z * DECAYF + OMDF * s.z;
        nw.w = w.w * DECAYF + OMDF * s.w;
        nc.x = nw.x / csk; nc.y = nw.y / csk; nc.z = nw.z / csk; nc.w = nw.w / csk;
        *reinterpret_cast<float4*>(w_out + (size_t)k * D + lane * 4) = nw;
        *reinterpret_cast<float4*>(cb_out + (size_t)k * D + lane * 4) = nc;
    }
}

extern "C" void kernel_launch(void* const* d_in, const int* in_sizes, int n_in,
                              void* d_out, int out_size, void* d_ws, size_t ws_size,
                              hipStream_t stream) {
    (void)in_sizes; (void)n_in; (void)out_size; (void)ws_size;
    const float* x      = (const float*)d_in[0];
    const float* cb     = (const float*)d_in[1];
    const float* ema_w  = (const float*)d_in[2];
    const float* ema_cs = (const float*)d_in[3];

    float* out    = (float*)d_out;
    float* quant  = out;
    float* enc    = quant + 16777216;
    float* cs_out = enc + 67108864;
    float* w_out  = cs_out + 1024;
    float* cb_out = w_out + 262144;

    float* ws      = (float*)d_ws;
    float* counts  = ws;                         // 1024 f
    float* cnorm   = ws + 1024;                  // 1024 f
    int*   offsets = (int*)(ws + 2048);          // 1024 i
    int*   cursor  = (int*)(ws + 3072);          // 1024 i
    int*   idx     = (int*)(ws + 4096);          // 65536 i
    int*   rowlist = (int*)(ws + 69632);         // 65536 i
    char*  wsB     = (char*)(ws + 135168);       // 1 MiB, 16B aligned

    hipMemsetAsync(counts, 0, 1024 * sizeof(float), stream);
    norms_kernel<<<K / 4, 256, 0, stream>>>(cb, cnorm);
    split_cb_kernel<<<256, 256, 0, stream>>>(cb, wsB);
    argmin_mfma_kernel<<<N_ROWS / 64, 256, 0, stream>>>(x, wsB, cnorm, idx, counts);
    quant_kernel<<<N_ROWS / 4, 256, 0, stream>>>(cb, idx, quant);
    enc_kernel<<<2048, 256, 0, stream>>>(idx, enc);
    cs_scan_kernel<<<1, 1024, 0, stream>>>(ema_cs, counts, cs_out, offsets, cursor);
    scatter_kernel<<<N_ROWS / 256, 256, 0, stream>>>(idx, cursor, rowlist);
    // after scatter, cursor[k] == end of code k's segment
    code_update_kernel<<<K, 256, 0, stream>>>(x, offsets, cursor, rowlist, ema_w,
                                              cs_out, w_out, cb_out);
}

// Round 3
// 339.808 us; speedup vs baseline: 3.3523x; 2.1363x over previous
//
#include <hip/hip_runtime.h>

#define N_ROWS 65536
#define D 256
#define K 1024
#define DECAYF 0.99f
#define OMDF 0.01f
#define EPSF 1e-5f

typedef _Float16 f16;
typedef _Float16 f16x8 __attribute__((ext_vector_type(8)));
typedef float f32x16 __attribute__((ext_vector_type(16)));

// ---------------- codebook norms (fp32, exact) ----------------
__global__ __launch_bounds__(256) void norms_kernel(const float* __restrict__ cb,
                                                    float* __restrict__ cnorm) {
    const int row = blockIdx.x * 4 + (threadIdx.x >> 6);
    const int lane = threadIdx.x & 63;
    const float4 v = *reinterpret_cast<const float4*>(cb + row * D + lane * 4);
    float s = v.x * v.x + v.y * v.y + v.z * v.z + v.w * v.w;
    #pragma unroll
    for (int m = 32; m; m >>= 1) s += __shfl_xor(s, m);
    if (lane == 0) cnorm[row] = s;
}

// ---------------- codebook split hi/lo fp16, pre-swizzled tile layout ----------------
__global__ __launch_bounds__(256) void split_cb_kernel(const float* __restrict__ cb,
                                                       char* __restrict__ wsB) {
    const int g = blockIdx.x * 256 + threadIdx.x;   // 0..65535
    const int sp = g & 15;
    const int c = (g >> 4) & 255;
    const int sd = g >> 12;                          // ct*4+dk
    const int ct = sd >> 2, dk = sd & 3;
    const int sl = sp ^ (c & 7);
    const int v = sl >> 3, ks = (sl >> 1) & 3, h = sl & 1;
    const float* src = cb + (size_t)(ct * 256 + c) * D + dk * 64 + ks * 16 + h * 8;
    f16 out[8];
    #pragma unroll
    for (int e = 0; e < 8; ++e) {
        const float f = src[e];
        const f16 hi = (f16)f;
        out[e] = v ? (f16)(f - (float)hi) : hi;
    }
    *reinterpret_cast<f16x8*>(wsB + (size_t)g * 16) = *reinterpret_cast<f16x8*>(out);
}

// ---------------- MFMA argmin ----------------
__global__ __launch_bounds__(256, 2) void argmin_mfma_kernel(
        const float* __restrict__ x, const char* __restrict__ wsB,
        const float* __restrict__ cnorm, int* __restrict__ idx_out,
        float* __restrict__ counts) {
    __shared__ char smem[81920];
    char* Alds = smem;
    char* Blds = smem + 16384;
    const int tid = threadIdx.x;
    const int wave = tid >> 6;
    const int lane = tid & 63;
    const int rw = wave >> 1;
    const int cw = wave & 1;
    const int l31 = lane & 31;
    const int h = lane >> 5;
    const int n0 = blockIdx.x * 64;

    float bestv[16];
    int besti[16];
    #pragma unroll
    for (int r = 0; r < 16; ++r) { bestv[r] = 3.4e38f; besti[r] = 0; }

    const int s_row = tid >> 2;
    const int s_c4 = tid & 3;

    for (int ct = 0; ct < 4; ++ct) {
        f32x16 acc[4];
        #pragma unroll
        for (int cf = 0; cf < 4; ++cf)
            #pragma unroll
            for (int r = 0; r < 16; ++r) acc[cf][r] = 0.f;

        for (int dks = 0; dks < 4; ++dks) {
            const int dk = (ct & 1) ? (3 - dks) : dks;
            __syncthreads();
            if (!(ct > 0 && dks == 0)) {
                const float4* xs = reinterpret_cast<const float4*>(
                    x + (size_t)(n0 + s_row) * D + dk * 64 + s_c4 * 16);
                float f[16];
                {
                    const float4 f0 = xs[0], f1 = xs[1], f2 = xs[2], f3 = xs[3];
                    f[0]=f0.x; f[1]=f0.y; f[2]=f0.z; f[3]=f0.w;
                    f[4]=f1.x; f[5]=f1.y; f[6]=f1.z; f[7]=f1.w;
                    f[8]=f2.x; f[9]=f2.y; f[10]=f2.z; f[11]=f2.w;
                    f[12]=f3.x; f[13]=f3.y; f[14]=f3.z; f[15]=f3.w;
                }
                f16 hi[16], lo[16];
                #pragma unroll
                for (int e = 0; e < 16; ++e) {
                    hi[e] = (f16)f[e];
                    lo[e] = (f16)(f[e] - (float)hi[e]);
                }
                const int sw = s_row & 7;
                char* Abase = Alds + s_row * 256;
                *reinterpret_cast<f16x8*>(Abase + (((s_c4 * 2 + 0) ^ sw) * 16)) = *reinterpret_cast<f16x8*>(&hi[0]);
                *reinterpret_cast<f16x8*>(Abase + (((s_c4 * 2 + 1) ^ sw) * 16)) = *reinterpret_cast<f16x8*>(&hi[8]);
                *reinterpret_cast<f16x8*>(Abase + (((8 + s_c4 * 2 + 0) ^ sw) * 16)) = *reinterpret_cast<f16x8*>(&lo[0]);
                *reinterpret_cast<f16x8*>(Abase + (((8 + s_c4 * 2 + 1) ^ sw) * 16)) = *reinterpret_cast<f16x8*>(&lo[8]);
            }
            {
                const int4* gsrc = reinterpret_cast<const int4*>(wsB + ((size_t)(ct * 4 + dk) << 16));
                int4* ldst = reinterpret_cast<int4*>(Blds);
                #pragma unroll
                for (int i = 0; i < 16; ++i) ldst[tid + i * 256] = gsrc[tid + i * 256];
            }
            __syncthreads();
            const int arow = rw * 32 + l31;
            const int asw = arow & 7;
            #pragma unroll
            for (int ks = 0; ks < 4; ++ks) {
                const int sA = ks * 2 + h;
                const f16x8 Ah = *reinterpret_cast<const f16x8*>(Alds + arow * 256 + ((sA ^ asw) * 16));
                const f16x8 Al = *reinterpret_cast<const f16x8*>(Alds + arow * 256 + (((8 + sA) ^ asw) * 16));
                #pragma unroll
                for (int cf = 0; cf < 4; ++cf) {
                    const int bcode = cw * 128 + cf * 32 + l31;
                    const char* Bbase = Blds + bcode * 256;
                    const int bsw = bcode & 7;
                    const f16x8 Bh = *reinterpret_cast<const f16x8*>(Bbase + ((sA ^ bsw) * 16));
                    const f16x8 Bl = *reinterpret_cast<const f16x8*>(Bbase + (((8 + sA) ^ bsw) * 16));
                    acc[cf] = __builtin_amdgcn_mfma_f32_32x32x16_f16(Ah, Bh, acc[cf], 0, 0, 0);
                    acc[cf] = __builtin_amdgcn_mfma_f32_32x32x16_f16(Ah, Bl, acc[cf], 0, 0, 0);
                    acc[cf] = __builtin_amdgcn_mfma_f32_32x32x16_f16(Al, Bh, acc[cf], 0, 0, 0);
                }
            }
        }
        #pragma unroll
        for (int cf = 0; cf < 4; ++cf) {
            const int code = ct * 256 + cw * 128 + cf * 32 + l31;
            const float cn = cnorm[code];
            #pragma unroll
            for (int r = 0; r < 16; ++r) {
                const float dist = cn - 2.f * acc[cf][r];
                if (dist < bestv[r]) { bestv[r] = dist; besti[r] = code; }
            }
        }
    }
    #pragma unroll
    for (int r = 0; r < 16; ++r) {
        float v = bestv[r];
        int b = besti[r];
        #pragma unroll
        for (int m = 16; m; m >>= 1) {
            const float ov = __shfl_xor(v, m);
            const int ob = __shfl_xor(b, m);
            if (ov < v || (ov == v && ob < b)) { v = ov; b = ob; }
        }
        bestv[r] = v; besti[r] = b;
    }
    __syncthreads();
    float* Sv = reinterpret_cast<float*>(smem);
    int*   Si = reinterpret_cast<int*>(smem + 512);
    if (l31 == 0) {
        #pragma unroll
        for (int r = 0; r < 16; ++r) {
            const int row = rw * 32 + (r & 3) + 8 * (r >> 2) + 4 * h;
            Sv[cw * 64 + row] = bestv[r];
            Si[cw * 64 + row] = besti[r];
        }
    }
    __syncthreads();
    if (tid < 64) {
        const float v0 = Sv[tid], v1 = Sv[64 + tid];
        const int b0 = Si[tid], b1 = Si[64 + tid];
        const bool take1 = (v1 < v0) || (v1 == v0 && b1 < b0);
        const int b = take1 ? b1 : b0;
        idx_out[n0 + tid] = b;
        atomicAdd(&counts[b], 1.0f);
    }
}

// ---------------- quantized gather ----------------
__global__ __launch_bounds__(256) void quant_kernel(const float* __restrict__ cb,
                                                    const int* __restrict__ idx,
                                                    float* __restrict__ quant) {
    const int n = blockIdx.x * 4 + (threadIdx.x >> 6);
    const int lane = threadIdx.x & 63;
    const int i = idx[n];
    const float4 c = *reinterpret_cast<const float4*>(cb + (size_t)i * D + lane * 4);
    *reinterpret_cast<float4*>(quant + (size_t)n * D + lane * 4) = c;
}

// ---------------- one-hot encodings ----------------
__global__ __launch_bounds__(256) void enc_kernel(const int* __restrict__ idx,
                                                  float* __restrict__ enc) {
    const int total = N_ROWS * (K / 4);
    for (int g = blockIdx.x * blockDim.x + threadIdx.x; g < total;
         g += gridDim.x * blockDim.x) {
        const int n = g >> 8;
        const int k0 = (g & 255) * 4;
        const int i = idx[n];
        float4 v;
        v.x = (k0 == i) ? 1.f : 0.f;
        v.y = (k0 + 1 == i) ? 1.f : 0.f;
        v.z = (k0 + 2 == i) ? 1.f : 0.f;
        v.w = (k0 + 3 == i) ? 1.f : 0.f;
        *reinterpret_cast<float4*>(enc + (size_t)g * 4) = v;
    }
}

// ---------------- cs EMA + Laplace + exclusive scan of counts ----------------
__global__ __launch_bounds__(1024) void cs_scan_kernel(const float* __restrict__ ema_cs,
                                                       const float* __restrict__ counts,
                                                       float* __restrict__ cs_out,
                                                       int* __restrict__ cursor) {
    __shared__ float red[16];
    __shared__ float n_sh;
    __shared__ int sc[1024];
    const int k = threadIdx.x;
    const float cnt = counts[k];
    const float c = ema_cs[k] * DECAYF + OMDF * cnt;
    float s = c;
    #pragma unroll
    for (int m = 32; m; m >>= 1) s += __shfl_xor(s, m);
    if ((k & 63) == 0) red[k >> 6] = s;
    const int ic = (int)cnt;
    sc[k] = ic;
    __syncthreads();
    if (k == 0) {
        float n = 0.f;
        for (int w = 0; w < 16; ++w) n += red[w];
        n_sh = n;
    }
    for (int d = 1; d < 1024; d <<= 1) {
        const int t = (k >= d) ? sc[k - d] : 0;
        __syncthreads();
        sc[k] += t;
        __syncthreads();
    }
    const float n = n_sh;
    cs_out[k] = (c + EPSF) / (n + c * EPSF) * n;
    cursor[k] = sc[k] - ic;
}

// ---------------- scatter rows (and their code) by code ----------------
__global__ __launch_bounds__(256) void scatter_kernel(const int* __restrict__ idx,
                                                      int* __restrict__ cursor,
                                                      int* __restrict__ rowlist,
                                                      int* __restrict__ codelist) {
    const int n = blockIdx.x * 256 + threadIdx.x;
    const int i = idx[n];
    const int pos = atomicAdd(&cursor[i], 1);
    rowlist[pos] = n;
    codelist[pos] = i;
}

// ---------------- balanced segmented sum over sorted rowlist ----------------
// 2048 blocks x 4 waves; each wave sums 8 consecutive sorted entries,
// flushing a partial float4 per lane to dw on code change (sorted => ~1 flush/wave).
__global__ __launch_bounds__(256) void chunk_sum_kernel(const float* __restrict__ x,
                                                        const int* __restrict__ rowlist,
                                                        const int* __restrict__ codelist,
                                                        float* __restrict__ dw) {
    const int wave = threadIdx.x >> 6;
    const int lane = threadIdx.x & 63;
    const int p0 = blockIdx.x * 32 + wave * 8;
    int rows[8], codes[8];
    #pragma unroll
    for (int j = 0; j < 8; ++j) {
        rows[j] = rowlist[p0 + j];
        codes[j] = codelist[p0 + j];
    }
    float4 v[8];
    #pragma unroll
    for (int j = 0; j < 8; ++j)
        v[j] = *reinterpret_cast<const float4*>(x + (size_t)rows[j] * D + lane * 4);
    float4 s = v[0];
    int cur = codes[0];
    #pragma unroll
    for (int j = 1; j < 8; ++j) {
        if (codes[j] != cur) {
            float* dst = dw + (size_t)cur * D + lane * 4;
            atomicAdd(dst + 0, s.x); atomicAdd(dst + 1, s.y);
            atomicAdd(dst + 2, s.z); atomicAdd(dst + 3, s.w);
            cur = codes[j];
            s = v[j];
        } else {
            s.x += v[j].x; s.y += v[j].y; s.z += v[j].z; s.w += v[j].w;
        }
    }
    float* dst = dw + (size_t)cur * D + lane * 4;
    atomicAdd(dst + 0, s.x); atomicAdd(dst + 1, s.y);
    atomicAdd(dst + 2, s.z); atomicAdd(dst + 3, s.w);
}

// ---------------- ema_w + new codebook ----------------
__global__ __launch_bounds__(256) void ema_kernel(const float* __restrict__ ema_w,
                                                  const float* __restrict__ dw,
                                                  const float* __restrict__ cs,
                                                  float* __restrict__ w_out,
                                                  float* __restrict__ cb_out) {
    const int e4 = blockIdx.x * blockDim.x + threadIdx.x;
    const int k = e4 >> 6;
    const float csk = cs[k];
    const float4 w = *reinterpret_cast<const float4*>(ema_w + (size_t)e4 * 4);
    const float4 d = *reinterpret_cast<const float4*>(dw + (size_t)e4 * 4);
    float4 nw, nc;
    nw.x = w.x * DECAYF + OMDF * d.x;
    nw.y = w.y * DECAYF + OMDF * d.y;
    nw.z = w.z * DECAYF + OMDF * d.z;
    nw.w = w.w * DECAYF + OMDF * d.w;
    nc.x = nw.x / csk; nc.y = nw.y / csk; nc.z = nw.z / csk; nc.w = nw.w / csk;
    *reinterpret_cast<float4*>(w_out + (size_t)e4 * 4) = nw;
    *reinterpret_cast<float4*>(cb_out + (size_t)e4 * 4) = nc;
}

extern "C" void kernel_launch(void* const* d_in, const int* in_sizes, int n_in,
                              void* d_out, int out_size, void* d_ws, size_t ws_size,
                              hipStream_t stream) {
    (void)in_sizes; (void)n_in; (void)out_size; (void)ws_size;
    const float* x      = (const float*)d_in[0];
    const float* cb     = (const float*)d_in[1];
    const float* ema_w  = (const float*)d_in[2];
    const float* ema_cs = (const float*)d_in[3];

    float* out    = (float*)d_out;
    float* quant  = out;
    float* enc    = quant + 16777216;
    float* cs_out = enc + 67108864;
    float* w_out  = cs_out + 1024;
    float* cb_out = w_out + 262144;

    float* ws       = (float*)d_ws;
    float* counts   = ws;                          // 1024 f
    float* dw       = ws + 1024;                   // 262144 f (zeroed with counts)
    float* cnorm    = ws + 263168;                 // 1024 f
    int*   cursor   = (int*)(ws + 264192);         // 1024 i
    int*   idx      = (int*)(ws + 265216);         // 65536 i
    int*   rowlist  = (int*)(ws + 330752);         // 65536 i
    int*   codelist = (int*)(ws + 396288);         // 65536 i
    char*  wsB      = (char*)(ws + 461824);        // 1 MiB, 16B aligned

    hipMemsetAsync(ws, 0, (size_t)(1024 + 262144) * sizeof(float), stream);
    norms_kernel<<<K / 4, 256, 0, stream>>>(cb, cnorm);
    split_cb_kernel<<<256, 256, 0, stream>>>(cb, wsB);
    argmin_mfma_kernel<<<N_ROWS / 64, 256, 0, stream>>>(x, wsB, cnorm, idx, counts);
    quant_kernel<<<N_ROWS / 4, 256, 0, stream>>>(cb, idx, quant);
    enc_kernel<<<2048, 256, 0, stream>>>(idx, enc);
    cs_scan_kernel<<<1, 1024, 0, stream>>>(ema_cs, counts, cs_out, cursor);
    scatter_kernel<<<N_ROWS / 256, 256, 0, stream>>>(idx, cursor, rowlist, codelist);
    chunk_sum_kernel<<<2048, 256, 0, stream>>>(x, rowlist, codelist, dw);
    ema_kernel<<<65536 / 256, 256, 0, stream>>>(ema_w, dw, cs_out, w_out, cb_out);
}